// Round 1
// baseline (165.740 us; speedup 1.0000x reference)
//
#include <hip/hip_runtime.h>
#include <hip/hip_bf16.h>
#include <stdint.h>

#define NTOK 49
#define DIM  128
#define NH   4
#define HD   32
#define QKVN 384
#define SCALE 0.17677669529663687f

typedef __bf16 bfloat_t;
typedef bfloat_t bf16x8 __attribute__((ext_vector_type(8)));
typedef bfloat_t bf16x4 __attribute__((ext_vector_type(4)));
typedef float f32x4 __attribute__((ext_vector_type(4)));

// ---- LDS layout (bytes). Row stride 136 bf16 elems (=272B, 17*16) ----
#define XS 136
#define X_OFF  0            // x bf16 [64][136]  (later: P region, then ao)
#define Q_OFF  17408        // q bf16 [64][136] (cols = head*32+d), pre-scaled
#define K_OFF  34816        // k bf16 [64][136]
#define VT_OFF 52224        // vT bf16 [128][72]: row = head*32+d, col = token
#define VTS 72
#define PS  72              // P per wave: [64][72] bf16, at wave*9216
#define P_BYTES 9216
#define SMEM_BYTES 70656

__global__ void prep_weights(const float* __restrict__ qkvw,
                             const float* __restrict__ projw,
                             bfloat_t* __restrict__ qkvw_b,
                             bfloat_t* __restrict__ projw_b) {
    int i = blockIdx.x * 256 + threadIdx.x;
    if (i < QKVN * DIM) qkvw_b[i] = (bfloat_t)qkvw[i];
    if (i < DIM * DIM)  projw_b[i] = (bfloat_t)projw[i];
}

// cmb[w][h][row(64)][col(64)] = bias_table[rel_index[row][col]][h] + mask[w][row][col]
// col>=49 -> -1e30 (kills softmax padding); row>=49 -> 0 (finite, rows unused)
__global__ void prep_cmb(const float* __restrict__ mask,
                         const float* __restrict__ bias_table,
                         const int* __restrict__ rel_index,
                         float* __restrict__ cmb) {
    int wh = blockIdx.x;            // w*NH + h
    int w = wh >> 2, h = wh & 3;
    for (int idx = threadIdx.x; idx < 4096; idx += 256) {
        int row = idx >> 6, col = idx & 63;
        float v;
        if (col >= NTOK)      v = -1e30f;
        else if (row >= NTOK) v = 0.f;
        else v = bias_table[rel_index[row * NTOK + col] * NH + h]
               + mask[(w * NTOK + row) * NTOK + col];
        cmb[(size_t)wh * 4096 + idx] = v;
    }
}

__global__ __launch_bounds__(256, 2)
void win_attn(const float* __restrict__ x,
              const float* __restrict__ qkv_b,
              const float* __restrict__ proj_b,
              const bfloat_t* __restrict__ qkvw,
              const bfloat_t* __restrict__ projw,
              const float* __restrict__ cmb,
              float* __restrict__ out, int nw) {
    __shared__ __align__(16) char smem[SMEM_BYTES];
    const int b    = blockIdx.x;
    const int tid  = threadIdx.x;
    const int wave = tid >> 6;
    const int lane = tid & 63;
    const int g = lane >> 4;     // 16-lane group (k-block / row-block)
    const int c = lane & 15;     // column-within-tile

    // ---- stage x: fp32 global -> bf16 LDS [64][136]; zero pad rows 49..63 ----
    {
        const f32x4* xg4 = (const f32x4*)(x + (size_t)b * (NTOK * DIM));
        #pragma unroll
        for (int i = 0; i < 7; ++i) {
            int idx = tid + i * 256;
            if (idx < NTOK * DIM / 4) {
                f32x4 v = xg4[idx];
                int e = idx * 4, row = e >> 7, col = e & 127;
                bf16x4 pk = { (bfloat_t)v.x, (bfloat_t)v.y, (bfloat_t)v.z, (bfloat_t)v.w };
                *(bf16x4*)(smem + X_OFF + (row * XS + col) * 2) = pk;
            }
        }
        #pragma unroll
        for (int i = 0; i < 2; ++i) {
            int idx = tid + i * 256;
            if (idx < (64 - NTOK) * DIM / 4) {
                int e = idx * 4, row = NTOK + (e >> 7), col = e & 127;
                bf16x4 z = { (bfloat_t)0.f, (bfloat_t)0.f, (bfloat_t)0.f, (bfloat_t)0.f };
                *(bf16x4*)(smem + X_OFF + (row * XS + col) * 2) = z;
            }
        }
    }
    __syncthreads();

    // ---- QKV GEMM: [64x128] @ [128x384]^T, wave owns 96 output cols ----
    {
        f32x4 acc[4][6];
        #pragma unroll
        for (int mt = 0; mt < 4; ++mt)
            #pragma unroll
            for (int nt = 0; nt < 6; ++nt) acc[mt][nt] = (f32x4){0.f, 0.f, 0.f, 0.f};
        const int WB = wave * 96;
        #pragma unroll
        for (int ks = 0; ks < 4; ++ks) {
            bf16x8 af[4];
            #pragma unroll
            for (int mt = 0; mt < 4; ++mt)
                af[mt] = *(const bf16x8*)(smem + X_OFF + ((mt * 16 + c) * XS + ks * 32 + g * 8) * 2);
            bf16x8 bfr[6];
            #pragma unroll
            for (int nt = 0; nt < 6; ++nt)
                bfr[nt] = *(const bf16x8*)(qkvw + (WB + nt * 16 + c) * DIM + ks * 32 + g * 8);
            #pragma unroll
            for (int mt = 0; mt < 4; ++mt)
                #pragma unroll
                for (int nt = 0; nt < 6; ++nt)
                    acc[mt][nt] = __builtin_amdgcn_mfma_f32_16x16x32_bf16(af[mt], bfr[nt], acc[mt][nt], 0, 0, 0);
        }
        // scatter to q / k / vT in LDS  (C/D layout: col=c, rows=g*4+r)
        #pragma unroll
        for (int nt = 0; nt < 6; ++nt) {
            const int N = WB + nt * 16 + c;
            const float qb = qkv_b[N];
            const int which  = N >> 7;      // 0=q 1=k 2=v (wave-uniform per nt)
            const int within = N & 127;     // head*32 + d
            #pragma unroll
            for (int mt = 0; mt < 4; ++mt) {
                const int row0 = mt * 16 + g * 4;
                if (which == 0) {
                    #pragma unroll
                    for (int r = 0; r < 4; ++r)
                        *(bfloat_t*)(smem + Q_OFF + ((row0 + r) * XS + within) * 2) =
                            (bfloat_t)((acc[mt][nt][r] + qb) * SCALE);
                } else if (which == 1) {
                    #pragma unroll
                    for (int r = 0; r < 4; ++r)
                        *(bfloat_t*)(smem + K_OFF + ((row0 + r) * XS + within) * 2) =
                            (bfloat_t)(acc[mt][nt][r] + qb);
                } else {
                    bf16x4 pk = { (bfloat_t)(acc[mt][nt][0] + qb),
                                  (bfloat_t)(acc[mt][nt][1] + qb),
                                  (bfloat_t)(acc[mt][nt][2] + qb),
                                  (bfloat_t)(acc[mt][nt][3] + qb) };
                    *(bf16x4*)(smem + VT_OFF + (within * VTS + row0) * 2) = pk;
                }
            }
        }
    }
    __syncthreads();

    // ---- attention: wave handles head h ----
    const int h = wave;
    float dinv[4][4];
    {
        f32x4 s[4][4];
        bf16x8 qf[4], kf[4];
        #pragma unroll
        for (int mt = 0; mt < 4; ++mt)
            qf[mt] = *(const bf16x8*)(smem + Q_OFF + ((mt * 16 + c) * XS + h * HD + g * 8) * 2);
        #pragma unroll
        for (int nt = 0; nt < 4; ++nt)
            kf[nt] = *(const bf16x8*)(smem + K_OFF + ((nt * 16 + c) * XS + h * HD + g * 8) * 2);
        const f32x4 zero = {0.f, 0.f, 0.f, 0.f};
        #pragma unroll
        for (int mt = 0; mt < 4; ++mt)
            #pragma unroll
            for (int nt = 0; nt < 4; ++nt)
                s[mt][nt] = __builtin_amdgcn_mfma_f32_16x16x32_bf16(qf[mt], kf[nt], zero, 0, 0, 0);
        __syncthreads();   // all S reads of q/k done; P region may clobber x/q/k-head

        // softmax (logits = S + cmb; q pre-scaled). rows owned per lane: mt*16+g*4+r
        const float* cw = cmb + (size_t)((b % nw) * NH + h) * 4096;
        #pragma unroll
        for (int mt = 0; mt < 4; ++mt) {
            #pragma unroll
            for (int r = 0; r < 4; ++r) {
                const int row = mt * 16 + g * 4 + r;
                float m = -1e30f;
                #pragma unroll
                for (int nt = 0; nt < 4; ++nt) {
                    float l = s[mt][nt][r] + cw[row * 64 + nt * 16 + c];
                    s[mt][nt][r] = l;
                    m = fmaxf(m, l);
                }
                m = fmaxf(m, __shfl_xor(m, 1));
                m = fmaxf(m, __shfl_xor(m, 2));
                m = fmaxf(m, __shfl_xor(m, 4));
                m = fmaxf(m, __shfl_xor(m, 8));
                float sum = 0.f;
                #pragma unroll
                for (int nt = 0; nt < 4; ++nt) {
                    float p = __expf(s[mt][nt][r] - m);
                    s[mt][nt][r] = p;
                    sum += p;
                }
                sum += __shfl_xor(sum, 1);
                sum += __shfl_xor(sum, 2);
                sum += __shfl_xor(sum, 4);
                sum += __shfl_xor(sum, 8);
                dinv[mt][r] = 1.f / sum;
            }
        }
        // write P (bf16) to this wave's region
        char* Pw = smem + wave * P_BYTES;
        #pragma unroll
        for (int mt = 0; mt < 4; ++mt)
            #pragma unroll
            for (int nt = 0; nt < 4; ++nt)
                #pragma unroll
                for (int r = 0; r < 4; ++r)
                    *(bfloat_t*)(Pw + ((mt * 16 + g * 4 + r) * PS + nt * 16 + c) * 2) =
                        (bfloat_t)s[mt][nt][r];
    }

    // ---- PV: o[64x32] = P[64x64] @ v[64x32] ----
    {
        char* Pw = smem + wave * P_BYTES;
        f32x4 o[4][2];
        #pragma unroll
        for (int mt = 0; mt < 4; ++mt)
            #pragma unroll
            for (int nt = 0; nt < 2; ++nt) o[mt][nt] = (f32x4){0.f, 0.f, 0.f, 0.f};
        #pragma unroll
        for (int ks = 0; ks < 2; ++ks) {
            bf16x8 pf[4];
            #pragma unroll
            for (int mt = 0; mt < 4; ++mt)
                pf[mt] = *(const bf16x8*)(Pw + ((mt * 16 + c) * PS + ks * 32 + g * 8) * 2);
            bf16x8 vf[2];
            #pragma unroll
            for (int nt = 0; nt < 2; ++nt)
                vf[nt] = *(const bf16x8*)(smem + VT_OFF + ((h * HD + nt * 16 + c) * VTS + ks * 32 + g * 8) * 2);
            #pragma unroll
            for (int mt = 0; mt < 4; ++mt)
                #pragma unroll
                for (int nt = 0; nt < 2; ++nt)
                    o[mt][nt] = __builtin_amdgcn_mfma_f32_16x16x32_bf16(pf[mt], vf[nt], o[mt][nt], 0, 0, 0);
        }
        #pragma unroll
        for (int mt = 0; mt < 4; ++mt)
            #pragma unroll
            for (int nt = 0; nt < 2; ++nt)
                #pragma unroll
                for (int r = 0; r < 4; ++r) o[mt][nt][r] *= dinv[mt][r];
        __syncthreads();   // all PV reads of P done; ao clobbers P of waves 0/1
        // ao[64][136] bf16 at offset 0; wave writes its head's 32 cols
        #pragma unroll
        for (int mt = 0; mt < 4; ++mt)
            #pragma unroll
            for (int nt = 0; nt < 2; ++nt)
                #pragma unroll
                for (int r = 0; r < 4; ++r)
                    *(bfloat_t*)(smem + X_OFF + ((mt * 16 + g * 4 + r) * XS + h * HD + nt * 16 + c) * 2) =
                        (bfloat_t)o[mt][nt][r];
    }
    __syncthreads();

    // ---- proj: [64x128] @ [128x128]^T, wave owns 32 cols; fp32 store ----
    {
        f32x4 po[4][2];
        #pragma unroll
        for (int mt = 0; mt < 4; ++mt)
            #pragma unroll
            for (int nt = 0; nt < 2; ++nt) po[mt][nt] = (f32x4){0.f, 0.f, 0.f, 0.f};
        const int WB2 = wave * 32;
        #pragma unroll
        for (int ks = 0; ks < 4; ++ks) {
            bf16x8 af[4];
            #pragma unroll
            for (int mt = 0; mt < 4; ++mt)
                af[mt] = *(const bf16x8*)(smem + X_OFF + ((mt * 16 + c) * XS + ks * 32 + g * 8) * 2);
            bf16x8 wf[2];
            #pragma unroll
            for (int nt = 0; nt < 2; ++nt)
                wf[nt] = *(const bf16x8*)(projw + (WB2 + nt * 16 + c) * DIM + ks * 32 + g * 8);
            #pragma unroll
            for (int mt = 0; mt < 4; ++mt)
                #pragma unroll
                for (int nt = 0; nt < 2; ++nt)
                    po[mt][nt] = __builtin_amdgcn_mfma_f32_16x16x32_bf16(af[mt], wf[nt], po[mt][nt], 0, 0, 0);
        }
        float* og = out + (size_t)b * (NTOK * DIM);
        #pragma unroll
        for (int nt = 0; nt < 2; ++nt) {
            const int n = WB2 + nt * 16 + c;
            const float pb = proj_b[n];
            #pragma unroll
            for (int mt = 0; mt < 4; ++mt)
                #pragma unroll
                for (int r = 0; r < 4; ++r) {
                    const int t = mt * 16 + g * 4 + r;
                    if (t < NTOK) og[t * DIM + n] = po[mt][nt][r] + pb;
                }
        }
    }
}

extern "C" void kernel_launch(void* const* d_in, const int* in_sizes, int n_in,
                              void* d_out, int out_size, void* d_ws, size_t ws_size,
                              hipStream_t stream) {
    (void)n_in; (void)out_size; (void)ws_size;
    const float* x          = (const float*)d_in[0];
    const float* mask       = (const float*)d_in[1];
    const float* qkv_w      = (const float*)d_in[2];
    const float* qkv_b      = (const float*)d_in[3];
    const float* proj_w     = (const float*)d_in[4];
    const float* proj_b     = (const float*)d_in[5];
    const float* bias_table = (const float*)d_in[6];
    const int*   rel_index  = (const int*)d_in[7];
    float* out = (float*)d_out;

    char* ws = (char*)d_ws;
    bfloat_t* qkvw_b = (bfloat_t*)ws;              // 98304 B
    bfloat_t* projw_b = (bfloat_t*)(ws + 98304);   // 32768 B
    float*    cmb     = (float*)(ws + 131072);     // nw*NH*64*64*4 B (4 MB @ nw=64)

    const int B  = in_sizes[0] / (NTOK * DIM);
    const int nw = in_sizes[1] / (NTOK * NTOK);

    prep_weights<<<dim3((QKVN * DIM + 255) / 256), dim3(256), 0, stream>>>(qkv_w, proj_w, qkvw_b, projw_b);
    prep_cmb<<<dim3(nw * NH), dim3(256), 0, stream>>>(mask, bias_table, rel_index, cmb);
    win_attn<<<dim3(B), dim3(256), 0, stream>>>(x, qkv_b, proj_b, qkvw_b, projw_b, cmb, out, nw);
}